// Round 1
// baseline (1284.662 us; speedup 1.0000x reference)
//
#include <hip/hip_runtime.h>

typedef unsigned short ushort_t;
typedef unsigned int   uint_t;

typedef ushort_t u16x8  __attribute__((ext_vector_type(8)));
typedef __bf16   bf16x8 __attribute__((ext_vector_type(8)));
typedef float    f32x4  __attribute__((ext_vector_type(4)));

#define DIMSZ 1024
#define NHEAD 16

__device__ __forceinline__ ushort_t f2bf(float f) {
  uint_t u = __builtin_bit_cast(uint_t, f);
  u += 0x7fffu + ((u >> 16) & 1u);          // round-to-nearest-even
  return (ushort_t)(u >> 16);
}
__device__ __forceinline__ float bf2f(ushort_t h) {
  uint_t u = ((uint_t)h) << 16;
  return __builtin_bit_cast(float, u);
}
__device__ __forceinline__ void lds_load16(const void* g, void* l) {
  __builtin_amdgcn_global_load_lds((const __attribute__((address_space(1))) void*)g,
                                   (__attribute__((address_space(3))) void*)l, 16, 0, 0);
}

// ---------- weight transpose + bf16 convert: dst[n*1024+k] = src[k*ld + n] ----------
__global__ __launch_bounds__(256) void wtrans(const float* __restrict__ src, int ld,
                                              ushort_t* __restrict__ dst) {
  int idx = blockIdx.x * 256 + threadIdx.x;
  int n = idx >> 10, k = idx & 1023;
  dst[idx] = f2bf(src[(size_t)k * ld + n]);
}

// ---------- GEMM: C[M,N](bf16) = cvt_bf16(A fp32 [M,1024]) @ Bt[N,1024]^T ----------
// 128x128 tile, BK=32, 4 waves (2x2), 16x16x32 bf16 MFMA. grid = (N/128, M/128).
__global__ __launch_bounds__(256) void gemm_xw(const float* __restrict__ A,
                                               const ushort_t* __restrict__ Bt,
                                               ushort_t* __restrict__ C, int ldc) {
  __shared__ ushort_t As[128 * 32];
  __shared__ ushort_t Bs[128 * 32];
  const int t = threadIdx.x;
  const int n0 = blockIdx.x * 128;
  const int m0 = blockIdx.y * 128;
  const int w = t >> 6, lane = t & 63;
  const int wm = w >> 1, wn = w & 1;
  const int lr = lane & 15, lk = lane >> 4;

  const f32x4 zero = {0.f, 0.f, 0.f, 0.f};
  f32x4 acc[4][4];
#pragma unroll
  for (int i = 0; i < 4; ++i)
#pragma unroll
    for (int j = 0; j < 4; ++j) acc[i][j] = zero;

  const int arow = t >> 1, acse = (t & 1) * 16;
  const float* aptr = A + (size_t)(m0 + arow) * DIMSZ + acse;

  const int bbyte = w * 2048 + lane * 16;
  const int n_b0 = (bbyte >> 1) >> 5,          kk_b0 = (bbyte >> 1) & 31;
  const int n_b1 = ((bbyte + 1024) >> 1) >> 5, kk_b1 = ((bbyte + 1024) >> 1) & 31;
  const ushort_t* bp0 = Bt + (size_t)(n0 + n_b0) * DIMSZ + kk_b0;
  const ushort_t* bp1 = Bt + (size_t)(n0 + n_b1) * DIMSZ + kk_b1;
  ushort_t* bd0 = &Bs[w * 1024];        // wave-uniform LDS base, HW adds lane*16B
  ushort_t* bd1 = &Bs[w * 1024 + 512];

  for (int kc = 0; kc < DIMSZ; kc += 32) {
    __syncthreads();
    lds_load16(bp0 + kc, bd0);
    lds_load16(bp1 + kc, bd1);
    f32x4 f0 = *(const f32x4*)(aptr + kc);
    f32x4 f1 = *(const f32x4*)(aptr + kc + 4);
    f32x4 f2 = *(const f32x4*)(aptr + kc + 8);
    f32x4 f3 = *(const f32x4*)(aptr + kc + 12);
    u16x8 w0, w1;
#pragma unroll
    for (int j = 0; j < 4; ++j) {
      w0[j] = f2bf(f0[j]); w0[4 + j] = f2bf(f1[j]);
      w1[j] = f2bf(f2[j]); w1[4 + j] = f2bf(f3[j]);
    }
    *(u16x8*)&As[arow * 32 + acse] = w0;
    *(u16x8*)&As[arow * 32 + acse + 8] = w1;
    __syncthreads();
    bf16x8 a[4], b[4];
#pragma unroll
    for (int mi = 0; mi < 4; ++mi)
      a[mi] = *(const bf16x8*)&As[(wm * 64 + mi * 16 + lr) * 32 + lk * 8];
#pragma unroll
    for (int ni = 0; ni < 4; ++ni)
      b[ni] = *(const bf16x8*)&Bs[(wn * 64 + ni * 16 + lr) * 32 + lk * 8];
#pragma unroll
    for (int mi = 0; mi < 4; ++mi)
#pragma unroll
      for (int ni = 0; ni < 4; ++ni)
        acc[mi][ni] = __builtin_amdgcn_mfma_f32_16x16x32_bf16(a[mi], b[ni], acc[mi][ni], 0, 0, 0);
  }

#pragma unroll
  for (int mi = 0; mi < 4; ++mi)
#pragma unroll
    for (int ni = 0; ni < 4; ++ni) {
      const int col = n0 + wn * 64 + ni * 16 + lr;
#pragma unroll
      for (int r = 0; r < 4; ++r) {
        const int row = m0 + wm * 64 + mi * 16 + lk * 4 + r;
        C[(size_t)row * ldc + col] = f2bf(acc[mi][ni][r]);
      }
    }
}

// ---------- attention: dots over 16 heads + softmax -> attn[B,16] fp32 ----------
__global__ __launch_bounds__(256) void attn_k(const ushort_t* __restrict__ qb,
                                              const ushort_t* __restrict__ kvb,
                                              float* __restrict__ attn) {
  int idx = blockIdx.x * 256 + threadIdx.x;
  int row = idx >> 4, h = idx & 15;
  const ushort_t* qp = qb + (size_t)row * 1024 + h * 64;
  const ushort_t* kp = kvb + (size_t)row * 2048 + h * 64;
  float s = 0.f;
#pragma unroll
  for (int i = 0; i < 64; i += 8) {
    u16x8 q8 = *(const u16x8*)(qp + i);
    u16x8 k8 = *(const u16x8*)(kp + i);
#pragma unroll
    for (int j = 0; j < 8; ++j) s += bf2f(q8[j]) * bf2f(k8[j]);
  }
  s *= 0.015625f;  // scale * scale = 0.125 * 0.125 (double-scale, faithful to ref)
  float m = s;
#pragma unroll
  for (int off = 8; off >= 1; off >>= 1) m = fmaxf(m, __shfl_xor(m, off, 16));
  float e = expf(s - m);
  float sum = e;
#pragma unroll
  for (int off = 8; off >= 1; off >>= 1) sum += __shfl_xor(sum, off, 16);
  attn[idx] = e / sum;
}

// ---------- proj GEMM: out[M,1024](f32) = (attn .* v)(bf16) @ Wpt^T + bias ----------
__global__ __launch_bounds__(256) void gemm_proj(const ushort_t* __restrict__ kvb,
                                                 const float* __restrict__ attn,
                                                 const ushort_t* __restrict__ Bt,
                                                 const float* __restrict__ bias,
                                                 float* __restrict__ out) {
  __shared__ ushort_t As[128 * 32];
  __shared__ ushort_t Bs[128 * 32];
  const int t = threadIdx.x;
  const int n0 = blockIdx.x * 128;
  const int m0 = blockIdx.y * 128;
  const int w = t >> 6, lane = t & 63;
  const int wm = w >> 1, wn = w & 1;
  const int lr = lane & 15, lk = lane >> 4;

  const f32x4 zero = {0.f, 0.f, 0.f, 0.f};
  f32x4 acc[4][4];
#pragma unroll
  for (int i = 0; i < 4; ++i)
#pragma unroll
    for (int j = 0; j < 4; ++j) acc[i][j] = zero;

  const int arow = t >> 1, acse = (t & 1) * 16;
  const ushort_t* vptr = kvb + (size_t)(m0 + arow) * 2048 + 1024 + acse;
  const float* atp = attn + (size_t)(m0 + arow) * NHEAD;

  const int bbyte = w * 2048 + lane * 16;
  const int n_b0 = (bbyte >> 1) >> 5,          kk_b0 = (bbyte >> 1) & 31;
  const int n_b1 = ((bbyte + 1024) >> 1) >> 5, kk_b1 = ((bbyte + 1024) >> 1) & 31;
  const ushort_t* bp0 = Bt + (size_t)(n0 + n_b0) * DIMSZ + kk_b0;
  const ushort_t* bp1 = Bt + (size_t)(n0 + n_b1) * DIMSZ + kk_b1;
  ushort_t* bd0 = &Bs[w * 1024];
  ushort_t* bd1 = &Bs[w * 1024 + 512];

  for (int kc = 0; kc < DIMSZ; kc += 32) {
    __syncthreads();
    lds_load16(bp0 + kc, bd0);
    lds_load16(bp1 + kc, bd1);
    float sc = atp[(kc + acse) >> 6];   // head = (k index)/64, constant over 16 elems
    u16x8 v0 = *(const u16x8*)(vptr + kc);
    u16x8 v1 = *(const u16x8*)(vptr + kc + 8);
    u16x8 w0, w1;
#pragma unroll
    for (int j = 0; j < 8; ++j) {
      w0[j] = f2bf(bf2f(v0[j]) * sc);
      w1[j] = f2bf(bf2f(v1[j]) * sc);
    }
    *(u16x8*)&As[arow * 32 + acse] = w0;
    *(u16x8*)&As[arow * 32 + acse + 8] = w1;
    __syncthreads();
    bf16x8 a[4], b[4];
#pragma unroll
    for (int mi = 0; mi < 4; ++mi)
      a[mi] = *(const bf16x8*)&As[(wm * 64 + mi * 16 + lr) * 32 + lk * 8];
#pragma unroll
    for (int ni = 0; ni < 4; ++ni)
      b[ni] = *(const bf16x8*)&Bs[(wn * 64 + ni * 16 + lr) * 32 + lk * 8];
#pragma unroll
    for (int mi = 0; mi < 4; ++mi)
#pragma unroll
      for (int ni = 0; ni < 4; ++ni)
        acc[mi][ni] = __builtin_amdgcn_mfma_f32_16x16x32_bf16(a[mi], b[ni], acc[mi][ni], 0, 0, 0);
  }

#pragma unroll
  for (int mi = 0; mi < 4; ++mi)
#pragma unroll
    for (int ni = 0; ni < 4; ++ni) {
      const int col = n0 + wn * 64 + ni * 16 + lr;
      const float bb = bias[col];
#pragma unroll
      for (int r = 0; r < 4; ++r) {
        const int row = m0 + wm * 64 + mi * 16 + lk * 4 + r;
        out[(size_t)row * 1024 + col] = acc[mi][ni][r] + bb;
      }
    }
}

extern "C" void kernel_launch(void* const* d_in, const int* in_sizes, int n_in,
                              void* d_out, int out_size, void* d_ws, size_t ws_size,
                              hipStream_t stream) {
  const float* x    = (const float*)d_in[0];  // [65536,1024]
  const float* y    = (const float*)d_in[1];  // [65536,1024]
  // d_in[2] = mask, unused
  const float* Wq   = (const float*)d_in[3];  // [1024,1024]
  const float* Wkv  = (const float*)d_in[4];  // [1024,2048]
  const float* Wp   = (const float*)d_in[5];  // [1024,1024]
  const float* bp   = (const float*)d_in[6];  // [1024]

  // workspace layout (needs ~396 MiB)
  char* ws = (char*)d_ws;
  ushort_t* Wqt  = (ushort_t*)(ws);                        //   2 MiB  [1024][1024] bf16, N-major
  ushort_t* Wkvt = (ushort_t*)(ws + (2ull  << 20));        //   4 MiB  [2048][1024] bf16 (k rows 0..1023, v rows 1024..2047)
  ushort_t* Wpt  = (ushort_t*)(ws + (6ull  << 20));        //   2 MiB  [1024][1024] bf16
  float*    attn = (float*)   (ws + (8ull  << 20));        //   4 MiB  [65536][16] f32
  ushort_t* qb   = (ushort_t*)(ws + (12ull << 20));        // 128 MiB  [65536][1024] bf16
  ushort_t* kvb  = (ushort_t*)(ws + (140ull << 20));       // 256 MiB  [65536][2048] bf16 (k | v)
  (void)in_sizes; (void)n_in; (void)out_size; (void)ws_size;

  // 1) weights -> bf16, transposed to [N][K]
  wtrans<<<4096, 256, 0, stream>>>(Wq, 1024, Wqt);
  wtrans<<<8192, 256, 0, stream>>>(Wkv, 2048, Wkvt);
  wtrans<<<4096, 256, 0, stream>>>(Wp, 1024, Wpt);

  // 2) q = x @ Wq ; kv = y @ Wkv   (bf16 outputs)
  gemm_xw<<<dim3(8, 512),  256, 0, stream>>>(x, Wqt,  qb,  1024);
  gemm_xw<<<dim3(16, 512), 256, 0, stream>>>(y, Wkvt, kvb, 2048);

  // 3) per-row head dots + softmax -> attn
  attn_k<<<4096, 256, 0, stream>>>(qb, kvb, attn);

  // 4) out = (attn .* v) @ Wproj + bproj   (f32 output)
  gemm_proj<<<dim3(8, 512), 256, 0, stream>>>(kvb, attn, Wpt, bp, (float*)d_out);
}

// Round 2
// 1089.786 us; speedup vs baseline: 1.1788x; 1.1788x over previous
//
#include <hip/hip_runtime.h>

typedef unsigned short ushort_t;
typedef unsigned int   uint_t;

typedef ushort_t u16x8  __attribute__((ext_vector_type(8)));
typedef __bf16   bf16x8 __attribute__((ext_vector_type(8)));
typedef float    f32x4  __attribute__((ext_vector_type(4)));

#define DIMSZ 1024

__device__ __forceinline__ ushort_t f2bf(float f) {
  uint_t u = __builtin_bit_cast(uint_t, f);
  u += 0x7fffu + ((u >> 16) & 1u);          // round-to-nearest-even
  return (ushort_t)(u >> 16);
}
__device__ __forceinline__ float bf2f(ushort_t h) {
  uint_t u = ((uint_t)h) << 16;
  return __builtin_bit_cast(float, u);
}
__device__ __forceinline__ void lds_load16(const void* g, void* l) {
  __builtin_amdgcn_global_load_lds((const __attribute__((address_space(1))) void*)g,
                                   (__attribute__((address_space(3))) void*)l, 16, 0, 0);
}

// ---------- tiled weight transpose + bf16: dst[n*1024+k] = src[k*ld + n] ----------
__global__ __launch_bounds__(256) void wtrans(const float* __restrict__ src, int ld,
                                              ushort_t* __restrict__ dst) {
  __shared__ ushort_t tile[32][33];
  const int bx = blockIdx.x;              // along n (ld)
  const int by = blockIdx.y;              // along k (1024)
  const int tx = threadIdx.x & 31, ty = threadIdx.x >> 5;   // 32 x 8
#pragma unroll
  for (int i = 0; i < 32; i += 8)
    tile[ty + i][tx] = f2bf(src[(size_t)(by * 32 + ty + i) * ld + bx * 32 + tx]);
  __syncthreads();
#pragma unroll
  for (int i = 0; i < 32; i += 8)
    dst[(size_t)(bx * 32 + ty + i) * 1024 + by * 32 + tx] = tile[tx][ty + i];
}

// ---------- fp32 -> bf16 convert (64M elements), grid-stride ----------
__global__ __launch_bounds__(256) void cvt_bf16(const float* __restrict__ s,
                                                ushort_t* __restrict__ d) {
  const size_t n8 = (size_t)65536 * 1024 / 8;   // 8M groups of 8
  const size_t stride = (size_t)gridDim.x * 256;
  for (size_t i = (size_t)blockIdx.x * 256 + threadIdx.x; i < n8; i += stride) {
    f32x4 f0 = *(const f32x4*)(s + i * 8);
    f32x4 f1 = *(const f32x4*)(s + i * 8 + 4);
    u16x8 o;
#pragma unroll
    for (int j = 0; j < 4; ++j) { o[j] = f2bf(f0[j]); o[4 + j] = f2bf(f1[j]); }
    *(u16x8*)(d + i * 8) = o;
  }
}

// ---------- clean bf16 GEMM: C[M,N] = A[M,1024] @ Bt[N,1024]^T ----------
// 128x128 tile, BK=32, 4 waves (2x2), 16x16x32 bf16 MFMA, both operands via
// global_load_lds width=16 (m97 structure). XCD-swizzled 1D grid.
// OUTF32=0: C bf16, ldc given. OUTF32=1: C f32 (+bias), ldc=1024.
template <int OUTF32>
__global__ __launch_bounds__(256) void gemm_bt(const ushort_t* __restrict__ A,
                                               const ushort_t* __restrict__ Bt,
                                               void* __restrict__ Cv,
                                               const float* __restrict__ bias,
                                               int ldc, int ncol_lg2) {
  __shared__ ushort_t As[128 * 32];
  __shared__ ushort_t Bs[128 * 32];
  const int t = threadIdx.x;
  // XCD-aware bijective swizzle (gridDim.x is a multiple of 8: 4096 / 8192)
  const int nb8 = gridDim.x >> 3;
  const int nbid = (blockIdx.x & 7) * nb8 + (blockIdx.x >> 3);
  const int n0 = (nbid & ((1 << ncol_lg2) - 1)) * 128;
  const int m0 = (nbid >> ncol_lg2) * 128;

  const int w = t >> 6, lane = t & 63;
  const int wm = w >> 1, wn = w & 1;
  const int lr = lane & 15, lk = lane >> 4;

  const f32x4 zero = {0.f, 0.f, 0.f, 0.f};
  f32x4 acc[4][4];
#pragma unroll
  for (int i = 0; i < 4; ++i)
#pragma unroll
    for (int j = 0; j < 4; ++j) acc[i][j] = zero;

  // staging: each wave moves 16 rows (64 lanes x 16B = 16 rows x 32 bf16) per issue
  const int rsub = lane >> 2;            // 0..15
  const int csub = (lane & 3) * 8;       // 0,8,16,24
  const ushort_t* ap0 = A + (size_t)(m0 + w * 16 + rsub) * DIMSZ + csub;
  const ushort_t* ap1 = ap0 + 64 * DIMSZ;
  const ushort_t* bp0 = Bt + (size_t)(n0 + w * 16 + rsub) * DIMSZ + csub;
  const ushort_t* bp1 = bp0 + 64 * DIMSZ;
  ushort_t* ad0 = &As[w * 512];          // wave-uniform LDS bases (HW adds lane*16B)
  ushort_t* ad1 = &As[2048 + w * 512];
  ushort_t* bd0 = &Bs[w * 512];
  ushort_t* bd1 = &Bs[2048 + w * 512];

  for (int kc = 0; kc < DIMSZ; kc += 32) {
    __syncthreads();
    lds_load16(ap0 + kc, ad0);
    lds_load16(ap1 + kc, ad1);
    lds_load16(bp0 + kc, bd0);
    lds_load16(bp1 + kc, bd1);
    __syncthreads();
    bf16x8 a[4], b[4];
#pragma unroll
    for (int mi = 0; mi < 4; ++mi)
      a[mi] = *(const bf16x8*)&As[(wm * 64 + mi * 16 + lr) * 32 + lk * 8];
#pragma unroll
    for (int ni = 0; ni < 4; ++ni)
      b[ni] = *(const bf16x8*)&Bs[(wn * 64 + ni * 16 + lr) * 32 + lk * 8];
#pragma unroll
    for (int mi = 0; mi < 4; ++mi)
#pragma unroll
      for (int ni = 0; ni < 4; ++ni)
        acc[mi][ni] = __builtin_amdgcn_mfma_f32_16x16x32_bf16(a[mi], b[ni], acc[mi][ni], 0, 0, 0);
  }

#pragma unroll
  for (int mi = 0; mi < 4; ++mi)
#pragma unroll
    for (int ni = 0; ni < 4; ++ni) {
      const int col = n0 + wn * 64 + ni * 16 + lr;
      float bb = 0.f;
      if (OUTF32) bb = bias[col];
#pragma unroll
      for (int r = 0; r < 4; ++r) {
        const int row = m0 + wm * 64 + mi * 16 + lk * 4 + r;
        if (OUTF32)
          ((float*)Cv)[(size_t)row * 1024 + col] = acc[mi][ni][r] + bb;
        else
          ((ushort_t*)Cv)[(size_t)row * ldc + col] = f2bf(acc[mi][ni][r]);
      }
    }
}

// ---------- attention: head dots + softmax, then ab = attn*v (bf16, in-place over qb) ----------
__global__ __launch_bounds__(256) void attn_k(ushort_t* __restrict__ qb,
                                              const ushort_t* __restrict__ kvb) {
  const int idx = blockIdx.x * 256 + threadIdx.x;
  const int row = idx >> 4, h = idx & 15;
  const ushort_t* qp = qb + (size_t)row * 1024 + h * 64;
  const ushort_t* kp = kvb + (size_t)row * 2048 + h * 64;
  const ushort_t* vp = kp + 1024;
  float s = 0.f;
#pragma unroll
  for (int i = 0; i < 64; i += 8) {
    u16x8 q8 = *(const u16x8*)(qp + i);
    u16x8 k8 = *(const u16x8*)(kp + i);
#pragma unroll
    for (int j = 0; j < 8; ++j) s += bf2f(q8[j]) * bf2f(k8[j]);
  }
  s *= 0.015625f;  // scale*scale = 0.125*0.125 (faithful double-scale)
  float m = s;
#pragma unroll
  for (int off = 8; off >= 1; off >>= 1) m = fmaxf(m, __shfl_xor(m, off, 16));
  float e = expf(s - m);
  float sum = e;
#pragma unroll
  for (int off = 8; off >= 1; off >>= 1) sum += __shfl_xor(sum, off, 16);
  const float wgt = e / sum;
  ushort_t* op = qb + (size_t)row * 1024 + h * 64;   // overwrite own q slice
#pragma unroll
  for (int i = 0; i < 64; i += 8) {
    u16x8 v8 = *(const u16x8*)(vp + i);
    u16x8 o8;
#pragma unroll
    for (int j = 0; j < 8; ++j) o8[j] = f2bf(bf2f(v8[j]) * wgt);
    *(u16x8*)(op + i) = o8;
  }
}

extern "C" void kernel_launch(void* const* d_in, const int* in_sizes, int n_in,
                              void* d_out, int out_size, void* d_ws, size_t ws_size,
                              hipStream_t stream) {
  const float* x   = (const float*)d_in[0];  // [65536,1024]
  const float* y   = (const float*)d_in[1];  // [65536,1024]
  // d_in[2] = mask, unused
  const float* Wq  = (const float*)d_in[3];  // [1024,1024]
  const float* Wkv = (const float*)d_in[4];  // [1024,2048]
  const float* Wp  = (const float*)d_in[5];  // [1024,1024]
  const float* bp  = (const float*)d_in[6];  // [1024]
  (void)in_sizes; (void)n_in; (void)out_size; (void)ws_size;

  // workspace layout (520 MiB total, buffers reused across phases)
  char* ws = (char*)d_ws;
  ushort_t* Wqt  = (ushort_t*)(ws);                     //   2 MiB [1024][1024] bf16 N-major
  ushort_t* Wkvt = (ushort_t*)(ws + (2ull   << 20));    //   4 MiB [2048][1024] bf16 (k|v)
  ushort_t* Wpt  = (ushort_t*)(ws + (6ull   << 20));    //   2 MiB [1024][1024] bf16
  ushort_t* qb   = (ushort_t*)(ws + (8ull   << 20));    // 128 MiB q -> later ab=attn*v
  ushort_t* kvb  = (ushort_t*)(ws + (136ull << 20));    // 256 MiB kv
  ushort_t* actb = (ushort_t*)(ws + (392ull << 20));    // 128 MiB yb, then reused as xb

  // weights -> bf16, transposed to [N][K]
  wtrans<<<dim3(32, 32), 256, 0, stream>>>(Wq, 1024, Wqt);
  wtrans<<<dim3(64, 32), 256, 0, stream>>>(Wkv, 2048, Wkvt);
  wtrans<<<dim3(32, 32), 256, 0, stream>>>(Wp, 1024, Wpt);

  // y -> bf16; kv = yb @ Wkv
  cvt_bf16<<<4096, 256, 0, stream>>>(y, actb);
  gemm_bt<0><<<8192, 256, 0, stream>>>(actb, Wkvt, kvb, nullptr, 2048, 4);

  // x -> bf16 (reuse buffer); q = xb @ Wq
  cvt_bf16<<<4096, 256, 0, stream>>>(x, actb);
  gemm_bt<0><<<4096, 256, 0, stream>>>(actb, Wqt, qb, nullptr, 1024, 3);

  // per-row head dots + softmax; qb <- attn .* v (bf16)
  attn_k<<<4096, 256, 0, stream>>>(qb, kvb);

  // out = ab @ Wproj + bproj (f32)
  gemm_bt<1><<<4096, 256, 0, stream>>>(qb, Wpt, d_out, bp, 1024, 3);
}

// Round 3
// 915.670 us; speedup vs baseline: 1.4030x; 1.1902x over previous
//
#include <hip/hip_runtime.h>

typedef unsigned short ushort_t;
typedef unsigned int   uint_t;

typedef ushort_t u16x8  __attribute__((ext_vector_type(8)));
typedef __bf16   bf16x8 __attribute__((ext_vector_type(8)));
typedef float    f32x4  __attribute__((ext_vector_type(4)));

#define DIMSZ 1024
#define NT 16   // K tiles of 64

__device__ __forceinline__ ushort_t f2bf(float f) {
  uint_t u = __builtin_bit_cast(uint_t, f);
  u += 0x7fffu + ((u >> 16) & 1u);          // round-to-nearest-even
  return (ushort_t)(u >> 16);
}
__device__ __forceinline__ float bf2f(ushort_t h) {
  uint_t u = ((uint_t)h) << 16;
  return __builtin_bit_cast(float, u);
}
__device__ __forceinline__ void lds_load16(const void* g, void* l) {
  __builtin_amdgcn_global_load_lds((const __attribute__((address_space(1))) void*)g,
                                   (__attribute__((address_space(3))) void*)l, 16, 0, 0);
}
#define SCHED0() __builtin_amdgcn_sched_barrier(0)
#define WBAR() do { SCHED0(); __builtin_amdgcn_s_barrier(); SCHED0(); } while (0)

// ---------- tiled weight transpose + bf16: dst[n*1024+k] = src[k*ld + n] ----------
__global__ __launch_bounds__(256) void wtrans(const float* __restrict__ src, int ld,
                                              ushort_t* __restrict__ dst) {
  __shared__ ushort_t tile[32][33];
  const int bx = blockIdx.x;              // along n (ld)
  const int by = blockIdx.y;              // along k (1024)
  const int tx = threadIdx.x & 31, ty = threadIdx.x >> 5;   // 32 x 8
#pragma unroll
  for (int i = 0; i < 32; i += 8)
    tile[ty + i][tx] = f2bf(src[(size_t)(by * 32 + ty + i) * ld + bx * 32 + tx]);
  __syncthreads();
#pragma unroll
  for (int i = 0; i < 32; i += 8)
    dst[(size_t)(bx * 32 + ty + i) * 1024 + by * 32 + tx] = tile[tx][ty + i];
}

// ---------- fp32 -> bf16 convert (64M elements), grid-stride ----------
__global__ __launch_bounds__(256) void cvt_bf16(const float* __restrict__ s,
                                                ushort_t* __restrict__ d) {
  const size_t n8 = (size_t)65536 * 1024 / 8;
  const size_t stride = (size_t)gridDim.x * 256;
  for (size_t i = (size_t)blockIdx.x * 256 + threadIdx.x; i < n8; i += stride) {
    f32x4 f0 = *(const f32x4*)(s + i * 8);
    f32x4 f1 = *(const f32x4*)(s + i * 8 + 4);
    u16x8 o;
#pragma unroll
    for (int j = 0; j < 4; ++j) { o[j] = f2bf(f0[j]); o[4 + j] = f2bf(f1[j]); }
    *(u16x8*)(d + i * 8) = o;
  }
}

// ---------- attention: head dots + softmax, then qb <- attn*v (bf16 in-place) ----------
__global__ __launch_bounds__(256) void attn_k(ushort_t* __restrict__ qb,
                                              const ushort_t* __restrict__ kvb) {
  const int idx = blockIdx.x * 256 + threadIdx.x;
  const int row = idx >> 4, h = idx & 15;
  const ushort_t* qp = qb + (size_t)row * 1024 + h * 64;
  const ushort_t* kp = kvb + (size_t)row * 2048 + h * 64;
  const ushort_t* vp = kp + 1024;
  float s = 0.f;
#pragma unroll
  for (int i = 0; i < 64; i += 8) {
    u16x8 q8 = *(const u16x8*)(qp + i);
    u16x8 k8 = *(const u16x8*)(kp + i);
#pragma unroll
    for (int j = 0; j < 8; ++j) s += bf2f(q8[j]) * bf2f(k8[j]);
  }
  s *= 0.015625f;  // scale*scale (faithful double-scale)
  float m = s;
#pragma unroll
  for (int off = 8; off >= 1; off >>= 1) m = fmaxf(m, __shfl_xor(m, off, 16));
  float e = expf(s - m);
  float sum = e;
#pragma unroll
  for (int off = 8; off >= 1; off >>= 1) sum += __shfl_xor(sum, off, 16);
  const float wgt = e / sum;
  ushort_t* op = qb + (size_t)row * 1024 + h * 64;
#pragma unroll
  for (int i = 0; i < 64; i += 8) {
    u16x8 v8 = *(const u16x8*)(vp + i);
    u16x8 o8;
#pragma unroll
    for (int j = 0; j < 8; ++j) o8[j] = f2bf(bf2f(v8[j]) * wgt);
    *(u16x8*)(op + i) = o8;
  }
}

// ---------- 256x256x(BK=64) 8-wave 8-phase bf16 GEMM: C = A[M,1024] @ Bt[N,1024]^T ----------
// LDS layout (ushort elems): A buf c at c*16384, as 4 blocks of 64 rows x 64 cols
//   (block q = rows [q*64, q*64+64), offset q*4096). B buf c at 32768 + c*16384,
//   plain [256][64] row-major. XOR swizzle: col_byte ^= (row&7)<<4 (both sides).
template <int OUTF32>
__global__ __launch_bounds__(512, 2) void gemm8(const ushort_t* __restrict__ A,
                                                const ushort_t* __restrict__ Bt,
                                                void* __restrict__ Cv,
                                                const float* __restrict__ bias,
                                                int ldc, int ncol_lg2) {
  __shared__ ushort_t lds[65536];
  const int t = threadIdx.x;
  const int nb8 = gridDim.x >> 3;                       // XCD-aware bijective swizzle
  const int nbid = (blockIdx.x & 7) * nb8 + (blockIdx.x >> 3);
  const int n0 = (nbid & ((1 << ncol_lg2) - 1)) * 256;
  const int m0 = (nbid >> ncol_lg2) * 256;
  const int w = t >> 6, lane = t & 63;
  const int wm = w >> 2, wn = w & 3;
  const int lr = lane & 15, lk = lane >> 4;
  const int w512 = w * 512;

  // staging source (per-thread, swizzle pre-applied to global column)
  const int srow = w * 8 + (lane >> 3);                 // 0..63 within a 64-row block
  const int scsw = ((lane & 7) * 16) ^ ((srow & 7) << 4);
  const ushort_t* aS = A + (size_t)(m0 + srow) * DIMSZ + (scsw >> 1);
  const ushort_t* bS = Bt + (size_t)(n0 + srow) * DIMSZ + (scsw >> 1);

  // fragment ds_read offsets (elems), swizzled
  const int cbe0 = (((lk * 16)) ^ ((lr & 7) << 4)) >> 1;         // ks=0
  const int cbe1 = ((64 + lk * 16) ^ ((lr & 7) << 4)) >> 1;      // ks=1
  const int aRB = lr * 64;
  const int bRB = 32768 + (wn * 64 + lr) * 64;

  f32x4 acc[8][4];
  const f32x4 zf = {0.f, 0.f, 0.f, 0.f};
#pragma unroll
  for (int i = 0; i < 8; ++i)
#pragma unroll
    for (int j = 0; j < 4; ++j) acc[i][j] = zf;
  bf16x8 a[4][2], b0[2][2], b1[2][2];

  // A half h (=mq) -> blocks {h, h+2}; B half h -> rows [h*128, h*128+128)
#define STAGE_A(cc, hh, tt) do {                                          \
    const ushort_t* s_ = aS + (size_t)(hh) * 65536 + (tt) * 64;           \
    ushort_t* d_ = lds + (cc) * 16384 + (hh) * 4096 + w512;               \
    lds_load16(s_, d_);                                                   \
    lds_load16(s_ + 131072, d_ + 8192); } while (0)
#define STAGE_B(cc, hh, tt) do {                                          \
    const ushort_t* s_ = bS + (size_t)(hh) * 131072 + (tt) * 64;          \
    ushort_t* d_ = lds + 32768 + (cc) * 16384 + (hh) * 8192 + w512;       \
    lds_load16(s_, d_);                                                   \
    lds_load16(s_ + 65536, d_ + 4096); } while (0)
#define LDA(cc, mq) do {                                                  \
    const ushort_t* Lp = lds + (cc) * 16384 + (wm * 2 + (mq)) * 4096 + aRB; \
    _Pragma("unroll") for (int j = 0; j < 4; ++j) {                       \
      a[j][0] = *(const bf16x8*)(Lp + j * 1024 + cbe0);                   \
      a[j][1] = *(const bf16x8*)(Lp + j * 1024 + cbe1); } } while (0)
#define LDB(cc, dst, nq) do {                                             \
    const ushort_t* Lp = lds + (cc) * 16384 + bRB + (nq) * 2048;          \
    _Pragma("unroll") for (int ni = 0; ni < 2; ++ni) {                    \
      dst[ni][0] = *(const bf16x8*)(Lp + ni * 1024 + cbe0);               \
      dst[ni][1] = *(const bf16x8*)(Lp + ni * 1024 + cbe1); } } while (0)
#define MMQ(mb, B, nb) do {                                               \
    _Pragma("unroll") for (int j = 0; j < 4; ++j)                         \
    _Pragma("unroll") for (int ni = 0; ni < 2; ++ni)                      \
    _Pragma("unroll") for (int ks = 0; ks < 2; ++ks)                      \
      acc[(mb) + j][(nb) + ni] = __builtin_amdgcn_mfma_f32_16x16x32_bf16( \
          a[j][ks], B[ni][ks], acc[(mb) + j][(nb) + ni], 0, 0, 0); } while (0)
#define TILE(S1, S2, VM, tv, c, nxt) do {                                 \
    LDA(c, 0); LDB(c, b0, 0);                                             \
    if (S1) STAGE_A(nxt, 1, (tv) + 1);                                    \
    WBAR();                                                               \
    __builtin_amdgcn_s_setprio(1); MMQ(0, b0, 0); __builtin_amdgcn_s_setprio(0); \
    WBAR();                                                               \
    LDB(c, b1, 1);                                                        \
    if (S2) STAGE_A(c, 0, (tv) + 2);                                      \
    WBAR();                                                               \
    __builtin_amdgcn_s_setprio(1); MMQ(0, b1, 2); __builtin_amdgcn_s_setprio(0); \
    WBAR();                                                               \
    LDA(c, 1);                                                            \
    if (S2) STAGE_B(c, 0, (tv) + 2);                                      \
    WBAR();                                                               \
    __builtin_amdgcn_s_setprio(1); MMQ(4, b1, 2); __builtin_amdgcn_s_setprio(0); \
    WBAR();                                                               \
    if (S2) STAGE_B(c, 1, (tv) + 2);                                      \
    if ((VM) == 6) { asm volatile("s_waitcnt vmcnt(6)" ::: "memory"); }   \
    else if ((VM) == 0) { asm volatile("s_waitcnt vmcnt(0)" ::: "memory"); } \
    WBAR();                                                               \
    __builtin_amdgcn_s_setprio(1); MMQ(4, b0, 0); __builtin_amdgcn_s_setprio(0); \
    WBAR();                                                               \
  } while (0)

  // prologue: tile0 {Ah0,Ah1,Bh0,Bh1}, tile1 {Ah0,Bh0,Bh1}; leave tile1's 3 halves in flight
  STAGE_A(0, 0, 0); STAGE_A(0, 1, 0); STAGE_B(0, 0, 0); STAGE_B(0, 1, 0);
  STAGE_A(1, 0, 1); STAGE_B(1, 0, 1); STAGE_B(1, 1, 1);
  asm volatile("s_waitcnt vmcnt(6)" ::: "memory");
  WBAR();

  for (int tt = 0; tt < 7; ++tt) {
    const int t0 = tt * 2;
    TILE(1, 1, 6, t0, 0, 1);
    TILE(1, 1, 6, t0 + 1, 1, 0);
  }
  TILE(1, 0, 0, 14, 0, 1);
  TILE(0, 0, -1, 15, 1, 0);

#undef TILE
#undef MMQ
#undef LDB
#undef LDA
#undef STAGE_B
#undef STAGE_A

  if (!OUTF32) {
    // bf16 epilogue: bounce through per-wave 16KB LDS slice for 128B-coalesced stores
    ushort_t* Cp = (ushort_t*)Cv;
    ushort_t* ep = lds + w * 8192;
#pragma unroll
    for (int mq = 0; mq < 2; ++mq)
#pragma unroll
      for (int j = 0; j < 4; ++j)
#pragma unroll
        for (int ni = 0; ni < 4; ++ni)
#pragma unroll
          for (int r = 0; r < 4; ++r) {
            const int row = mq * 64 + j * 16 + lk * 4 + r;
            const int ce = ((ni * 16 + lr) * 2) ^ ((row & 7) << 4);
            ep[row * 64 + (ce >> 1)] = f2bf(acc[mq * 4 + j][ni][r]);
          }
#pragma unroll
    for (int rr = 0; rr < 16; ++rr) {
      const int row = rr * 8 + (lane >> 3);
      const int ce = ((lane & 7) * 16) ^ ((lane >> 3) << 4);
      u16x8 vv = *(const u16x8*)(ep + row * 64 + (ce >> 1));
      *(u16x8*)(Cp + (size_t)(m0 + wm * 128 + row) * ldc + n0 + wn * 64 + (lane & 7) * 8) = vv;
    }
  } else {
    float* Op = (float*)Cv;
    float bb[4];
#pragma unroll
    for (int ni = 0; ni < 4; ++ni) bb[ni] = bias[n0 + wn * 64 + ni * 16 + lr];
#pragma unroll
    for (int mq = 0; mq < 2; ++mq)
#pragma unroll
      for (int j = 0; j < 4; ++j)
#pragma unroll
        for (int ni = 0; ni < 4; ++ni)
#pragma unroll
          for (int r = 0; r < 4; ++r)
            Op[(size_t)(m0 + wm * 128 + mq * 64 + j * 16 + lk * 4 + r) * 1024 +
               n0 + wn * 64 + ni * 16 + lr] = acc[mq * 4 + j][ni][r] + bb[ni];
  }
}

extern "C" void kernel_launch(void* const* d_in, const int* in_sizes, int n_in,
                              void* d_out, int out_size, void* d_ws, size_t ws_size,
                              hipStream_t stream) {
  const float* x   = (const float*)d_in[0];
  const float* y   = (const float*)d_in[1];
  const float* Wq  = (const float*)d_in[3];
  const float* Wkv = (const float*)d_in[4];
  const float* Wp  = (const float*)d_in[5];
  const float* bp  = (const float*)d_in[6];
  (void)in_sizes; (void)n_in; (void)out_size; (void)ws_size;

  char* ws = (char*)d_ws;
  ushort_t* Wqt  = (ushort_t*)(ws);                     //   2 MiB [1024][1024]
  ushort_t* Wkvt = (ushort_t*)(ws + (2ull   << 20));    //   4 MiB [2048][1024] (k|v)
  ushort_t* Wpt  = (ushort_t*)(ws + (6ull   << 20));    //   2 MiB [1024][1024]
  ushort_t* qb   = (ushort_t*)(ws + (8ull   << 20));    // 128 MiB q -> ab=attn*v
  ushort_t* kvb  = (ushort_t*)(ws + (136ull << 20));    // 256 MiB kv
  ushort_t* actb = (ushort_t*)(ws + (392ull << 20));    // 128 MiB yb then xb

  wtrans<<<dim3(32, 32), 256, 0, stream>>>(Wq, 1024, Wqt);
  wtrans<<<dim3(64, 32), 256, 0, stream>>>(Wkv, 2048, Wkvt);
  wtrans<<<dim3(32, 32), 256, 0, stream>>>(Wp, 1024, Wpt);

  cvt_bf16<<<4096, 256, 0, stream>>>(y, actb);
  gemm8<0><<<2048, 512, 0, stream>>>(actb, Wkvt, kvb, nullptr, 2048, 3);

  cvt_bf16<<<4096, 256, 0, stream>>>(x, actb);
  gemm8<0><<<1024, 512, 0, stream>>>(actb, Wqt, qb, nullptr, 1024, 2);

  attn_k<<<4096, 256, 0, stream>>>(qb, kvb);

  gemm8<1><<<1024, 512, 0, stream>>>(qb, Wpt, d_out, bp, 1024, 2);
}